// Round 9
// baseline (245.552 us; speedup 1.0000x reference)
//
#include <hip/hip_runtime.h>

#define NN 50000
#define NE 800000
#define D  64
#define NB 782        // buckets of 64 nodes: ceil(50000/64)
#define NBLK 256      // phase-1/2 blocks
#define CHUNK 3125    // NBLK * CHUNK == NE exactly

// bf16 helpers (raw ushort storage, fp32 math)
__device__ __forceinline__ float blo(unsigned u) { return __uint_as_float(u << 16); }
__device__ __forceinline__ float bhi(unsigned u) { return __uint_as_float(u & 0xFFFF0000u); }
__device__ __forceinline__ unsigned short f2b(float f) {   // round-to-nearest-even
    unsigned u = __float_as_uint(f);
    return (unsigned short)((u + 0x7FFFu + ((u >> 16) & 1u)) >> 16);
}

// ---- phase 1: per-chunk LDS histogram over 782 buckets ----
__global__ __launch_bounds__(256) void p1_hist(const int* __restrict__ dst, int* __restrict__ M) {
    __shared__ int lh[NB];
    int t = threadIdx.x;
    for (int i = t; i < NB; i += 256) lh[i] = 0;
    __syncthreads();
    int e0 = blockIdx.x * CHUNK;
    for (int e = e0 + t; e < e0 + CHUNK; e += 256) {
        unsigned d = (unsigned)dst[e];
        if (d < NN) atomicAdd(&lh[d >> 6], 1);
    }
    __syncthreads();
    for (int i = t; i < NB; i += 256) M[blockIdx.x * NB + i] = lh[i];
}

// ---- scan A: one block per bucket — scan the 256 chunk-counts of column b ----
__global__ __launch_bounds__(256) void p_scan_a(int* __restrict__ M, int* __restrict__ btot) {
    __shared__ int sd[256];
    int b = blockIdx.x, t = threadIdx.x;
    int v = M[t * NB + b];
    sd[t] = v;
    __syncthreads();
    for (int off = 1; off < 256; off <<= 1) {
        int add = (t >= off) ? sd[t - off] : 0;
        __syncthreads();
        sd[t] += add;
        __syncthreads();
    }
    M[t * NB + b] = sd[t] - v;            // exclusive within bucket
    if (t == 255) btot[b] = sd[255];
}

// ---- scan B: exclusive scan of 782 bucket totals ----
__global__ __launch_bounds__(1024) void p_scan_b(const int* __restrict__ btot,
                                                 int* __restrict__ bucket_base) {
    __shared__ int sd[1024];
    int t = threadIdx.x;
    int v = (t < NB) ? btot[t] : 0;
    sd[t] = v;
    __syncthreads();
    for (int off = 1; off < 1024; off <<= 1) {
        int add = (t >= off) ? sd[t - off] : 0;
        __syncthreads();
        sd[t] += add;
        __syncthreads();
    }
    if (t < NB) bucket_base[t] = sd[t] - v;
    if (t == NB - 1) bucket_base[NB] = sd[t];
}

// ---- phase 2: scatter edges to bucket-sorted staging (LDS cursors, no global atomics) ----
__global__ __launch_bounds__(256) void p2_scatter(const int* __restrict__ src,
        const int* __restrict__ dst, const float* __restrict__ w,
        const int* __restrict__ M, const int* __restrict__ bucket_base,
        int2* __restrict__ stage) {
    __shared__ int lcur[NB];
    int t = threadIdx.x;
    for (int i = t; i < NB; i += 256)
        lcur[i] = M[blockIdx.x * NB + i] + bucket_base[i];
    __syncthreads();
    int e0 = blockIdx.x * CHUNK;
    for (int e = e0 + t; e < e0 + CHUNK; e += 256) {
        unsigned d = (unsigned)dst[e];
        unsigned s = (unsigned)src[e];
        if (d < NN) {
            int pos = atomicAdd(&lcur[d >> 6], 1);          // LDS atomic
            int2 pk;
            pk.x = (int)((s & 0xFFFFu) | ((d & 63u) << 16)); // src fits 16 bits
            pk.y = __float_as_int(w[e]);
            stage[pos] = pk;
        }
    }
}

// ---- phase 3: sort each 64-node bucket into exact rows; emit row_start + dinv ----
__global__ __launch_bounds__(256) void p3_sort(const int2* __restrict__ stage,
        const int* __restrict__ bucket_base, int2* __restrict__ csr,
        int* __restrict__ row_start, float* __restrict__ dinv) {
    __shared__ int   hist[64];
    __shared__ int   cur[64];
    __shared__ float wsum[64];
    int b = blockIdx.x, t = threadIdx.x;
    int g0 = bucket_base[b], g1 = bucket_base[b + 1];
    if (t < 64) { hist[t] = 0; wsum[t] = 0.f; }
    __syncthreads();
    for (int j = g0 + t; j < g1; j += 256) {
        int2 pk = stage[j];
        int r = (pk.x >> 16) & 63;
        atomicAdd(&hist[r], 1);
        atomicAdd(&wsum[r], __int_as_float(pk.y));   // fused weighted degree
    }
    __syncthreads();
    if (t == 0) {
        int s = g0;
        for (int r = 0; r < 64; ++r) { cur[r] = s; s += hist[r]; }
    }
    __syncthreads();
    if (t < 64) {
        int n = b * 64 + t;
        if (n < NN) {
            row_start[n] = cur[t];
            dinv[n] = rsqrtf(wsum[t] + 1.0f);
        }
    }
    __syncthreads();
    for (int j = g0 + t; j < g1; j += 256) {
        int2 pk = stage[j];
        int r = (pk.x >> 16) & 63;
        int pos = atomicAdd(&cur[r], 1);
        csr[pos] = make_int2(pk.x & 0xFFFF, pk.y);
    }
    if (b == 0 && t == 0) row_start[NN] = bucket_base[NB];
}

// hp planes: hpA[n][0:32), hpB[n][32:64) — each NN*32 bf16 = 3.2 MB (< 4 MB per-XCD L2)
__global__ __launch_bounds__(256) void gemm_pre_kernel(const float* __restrict__ x,
        const float* __restrict__ W, const float* __restrict__ dinv,
        unsigned short* __restrict__ hpA, unsigned short* __restrict__ hpB) {
    __shared__ float xs[16][64];
    int t = threadIdx.x;
    int base = blockIdx.x * 16;
    for (int idx = t; idx < 16 * 64; idx += 256)
        xs[idx >> 6][idx & 63] = x[(size_t)(base + (idx >> 6)) * 64 + (idx & 63)];
    __syncthreads();
    int col = t & 63, rq = t >> 6;
    float wc[64];
#pragma unroll
    for (int k = 0; k < 64; ++k) wc[k] = W[k * 64 + col];
    float acc0 = 0.f, acc1 = 0.f, acc2 = 0.f, acc3 = 0.f;
#pragma unroll
    for (int k = 0; k < 64; ++k) {
        float wk = wc[k];
        acc0 += xs[rq     ][k] * wk;
        acc1 += xs[rq +  4][k] * wk;
        acc2 += xs[rq +  8][k] * wk;
        acc3 += xs[rq + 12][k] * wk;
    }
    int r = base + rq;
    unsigned short* hpP = (col < 32) ? hpA : hpB;
    int c = col & 31;
    hpP[(size_t)(r     ) * 32 + c] = f2b(dinv[r     ] * acc0);
    hpP[(size_t)(r +  4) * 32 + c] = f2b(dinv[r +  4] * acc1);
    hpP[(size_t)(r +  8) * 32 + c] = f2b(dinv[r +  8] * acc2);
    hpP[(size_t)(r + 12) * 32 + c] = f2b(dinv[r + 12] * acc3);
}

// one feature-half pass: quarter-wave per node, lane = uint (2 bf16 feats of this half).
// Random re-reads stay within one 3.2 MB plane -> per-XCD L2 resident.
__global__ __launch_bounds__(256) void gather_kernel(const int* __restrict__ row_start,
        const int2* __restrict__ csr, const float* __restrict__ dinv,
        const unsigned* __restrict__ hp16, const float2* __restrict__ bias2,
        float2* __restrict__ out2) {
    int t = threadIdx.x;
    int lane = t & 63;
    int q = lane >> 4;              // quarter id within wave
    int fq = lane & 15;             // feature-pair id within half
    int n = blockIdx.x * 16 + ((t >> 6) << 2) + q;   // 4 waves x 4 nodes
    int qbase = q << 4;
    int s0 = row_start[n], s1 = row_start[n + 1];
    unsigned self = hp16[(size_t)n * 16 + fq];
    float ax = blo(self), ay = bhi(self);
    float bx = 0.f, by = 0.f;
    for (int base = s0; base < s1; base += 16) {
        int j = base + fq;
        int si = 0; float wl = 0.f;
        if (j < s1) {
            int2 pk = csr[j];
            si = pk.x;
            wl = __int_as_float(pk.y);
        }
        int m = s1 - base; if (m > 16) m = 16;
        int jj = 0;
        for (; jj + 4 <= m; jj += 4) {
            int a0 = __shfl(si, qbase + jj + 0); float w0 = __shfl(wl, qbase + jj + 0);
            int a1 = __shfl(si, qbase + jj + 1); float w1 = __shfl(wl, qbase + jj + 1);
            int a2 = __shfl(si, qbase + jj + 2); float w2 = __shfl(wl, qbase + jj + 2);
            int a3 = __shfl(si, qbase + jj + 3); float w3 = __shfl(wl, qbase + jj + 3);
            unsigned u0 = hp16[(size_t)a0 * 16 + fq];
            unsigned u1 = hp16[(size_t)a1 * 16 + fq];
            unsigned u2 = hp16[(size_t)a2 * 16 + fq];
            unsigned u3 = hp16[(size_t)a3 * 16 + fq];
            ax += w0 * blo(u0); ay += w0 * bhi(u0);
            bx += w1 * blo(u1); by += w1 * bhi(u1);
            ax += w2 * blo(u2); ay += w2 * bhi(u2);
            bx += w3 * blo(u3); by += w3 * bhi(u3);
        }
        for (; jj < m; ++jj) {
            int a0 = __shfl(si, qbase + jj); float w0 = __shfl(wl, qbase + jj);
            unsigned u0 = hp16[(size_t)a0 * 16 + fq];
            ax += w0 * blo(u0); ay += w0 * bhi(u0);
        }
    }
    float dv = dinv[n];
    float2 bb = bias2[fq];
    float2 r;
    r.x = dv * (ax + bx) + bb.x;
    r.y = dv * (ay + by) + bb.y;
    r.x = r.x > 0.f ? r.x : 0.f;
    r.y = r.y > 0.f ? r.y : 0.f;
    out2[(size_t)n * 32 + fq] = r;
}

extern "C" void kernel_launch(void* const* d_in, const int* in_sizes, int n_in,
                              void* d_out, int out_size, void* d_ws, size_t ws_size,
                              hipStream_t stream) {
    const float* x  = (const float*)d_in[0];
    const int*   ei = (const int*)d_in[1];    // int32 [2, NE] flat
    const float* ew = (const float*)d_in[2];
    const float* W0 = (const float*)d_in[3];
    const float* b0 = (const float*)d_in[4];
    const float* W1 = (const float*)d_in[5];
    const float* b1 = (const float*)d_in[6];
    const float* W2 = (const float*)d_in[7];
    const float* b2 = (const float*)d_in[8];
    float*       out = (float*)d_out;

    const int* src = ei;
    const int* dst = ei + NE;

    // workspace layout (int2 arrays first for 8B alignment), ~21 MB total
    int2*  stage       = (int2*)d_ws;                    // NE
    int2*  csr         = stage + NE;                     // NE
    int*   M           = (int*)(csr + NE);               // NBLK*NB
    int*   btot        = M + NBLK * NB;                  // NB
    int*   bucket_base = btot + NB;                      // NB+1
    int*   row_start   = bucket_base + NB + 1;           // NN+1
    float* dinv        = (float*)(row_start + NN + 1);   // NN
    unsigned short* hpA = (unsigned short*)(dinv + NN);  // NN*32 bf16 (3.2 MB)
    unsigned short* hpB = hpA + (size_t)NN * 32;         // NN*32 bf16 (3.2 MB)

    // ---- CSR build (no global atomics; once, shared by all 3 layers) ----
    p1_hist<<<NBLK, 256, 0, stream>>>(dst, M);
    p_scan_a<<<NB, 256, 0, stream>>>(M, btot);
    p_scan_b<<<1, 1024, 0, stream>>>(btot, bucket_base);
    p2_scatter<<<NBLK, 256, 0, stream>>>(src, dst, ew, M, bucket_base, stage);
    p3_sort<<<NB, 256, 0, stream>>>(stage, bucket_base, csr, row_start, dinv);

    const float* Ws[3] = {W0, W1, W2};
    const float* bs[3] = {b0, b1, b2};
    const float* in = x;
    for (int l = 0; l < 3; ++l) {
        gemm_pre_kernel<<<NN / 16, 256, 0, stream>>>(in, Ws[l], dinv, hpA, hpB);
        // pass A: feature half [0,32) — working set = hpA only (3.2 MB, L2-resident)
        gather_kernel<<<NN / 16, 256, 0, stream>>>(row_start, csr, dinv,
                (const unsigned*)hpA, (const float2*)bs[l], (float2*)out);
        // pass B: feature half [32,64)
        gather_kernel<<<NN / 16, 256, 0, stream>>>(row_start, csr, dinv,
                (const unsigned*)hpB, (const float2*)bs[l] + 16, (float2*)out + 16);
        in = out;   // stream-ordered: next gemm reads out after both passes
    }
}

// Round 10
// 201.015 us; speedup vs baseline: 1.2216x; 1.2216x over previous
//
#include <hip/hip_runtime.h>

#define NN 50000
#define NE 800000
#define D  64
#define NB 782        // buckets of 64 nodes: ceil(50000/64)
#define NBLK 256      // p12 blocks
#define CHUNK 3125    // NBLK * CHUNK == NE exactly
#define CAP 1536      // per-bucket slot cap (mean 1024, +6 sigma ~ 1216)
#define CAPTOT (NB * CAP)

// bf16 helpers (raw ushort storage, fp32 math)
__device__ __forceinline__ float blo(unsigned u) { return __uint_as_float(u << 16); }
__device__ __forceinline__ float bhi(unsigned u) { return __uint_as_float(u & 0xFFFF0000u); }
__device__ __forceinline__ unsigned short f2b(float f) {   // round-to-nearest-even
    unsigned u = __float_as_uint(f);
    return (unsigned short)((u + 0x7FFFu + ((u >> 16) & 1u)) >> 16);
}

// ---- init: fixed-stride bucket cursors ----
__global__ void k_init(int* __restrict__ cursor) {
    int i = blockIdx.x * blockDim.x + threadIdx.x;
    if (i < NB) cursor[i] = i * CAP;
}

// ---- single-pass bucket scatter: LDS-stage chunk, LDS hist, global reserve, scatter ----
__global__ __launch_bounds__(256) void p12(const int* __restrict__ src,
        const int* __restrict__ dst, const float* __restrict__ w,
        int* __restrict__ cursor, int2* __restrict__ stage) {
    __shared__ unsigned se[CHUNK];
    __shared__ float    sw[CHUNK];
    __shared__ int      lh[NB];
    int t = threadIdx.x;
    for (int i = t; i < NB; i += 256) lh[i] = 0;
    __syncthreads();
    int e0 = blockIdx.x * CHUNK;
    for (int i = t; i < CHUNK; i += 256) {
        int e = e0 + i;
        unsigned d = (unsigned)dst[e];
        unsigned s = (unsigned)src[e];
        float wv = w[e];
        unsigned pk = 0xFFFFFFFFu;   // invalid marker (bucket 1023 >= NB)
        if (d < NN) {
            pk = (s & 0xFFFFu) | ((d & 63u) << 16) | ((d >> 6) << 22);
            atomicAdd(&lh[d >> 6], 1);
        }
        se[i] = pk;
        sw[i] = wv;
    }
    __syncthreads();
    for (int i = t; i < NB; i += 256) {
        int c = lh[i];
        lh[i] = c ? atomicAdd(&cursor[i], c) : 0;   // lh becomes global write cursor
    }
    __syncthreads();
    for (int i = t; i < CHUNK; i += 256) {
        unsigned pk = se[i];
        if (pk != 0xFFFFFFFFu) {
            int bucket = (int)(pk >> 22);
            int pos = atomicAdd(&lh[bucket], 1);    // LDS atomic
            if (pos < (bucket + 1) * CAP)
                stage[pos] = make_int2((int)(pk & 0x3FFFFFu), __float_as_int(sw[i]));
        }
    }
}

// ---- per-bucket row sort: stage -> csr (padded layout); emit row_ptr/row_deg/dinv ----
__global__ __launch_bounds__(256) void p3_sort(const int2* __restrict__ stage,
        const int* __restrict__ cursor, int2* __restrict__ csr,
        int* __restrict__ row_ptr, int* __restrict__ row_deg, float* __restrict__ dinv) {
    __shared__ int   hist[64];
    __shared__ int   cur[64];
    __shared__ float wsum[64];
    int b = blockIdx.x, t = threadIdx.x;
    int g0 = b * CAP, g1 = cursor[b];
    if (t < 64) { hist[t] = 0; wsum[t] = 0.f; }
    __syncthreads();
    for (int j = g0 + t; j < g1; j += 256) {
        int2 pk = stage[j];
        int r = (pk.x >> 16) & 63;
        atomicAdd(&hist[r], 1);
        atomicAdd(&wsum[r], __int_as_float(pk.y));   // fused weighted degree
    }
    __syncthreads();
    if (t == 0) {
        int s = g0;
        for (int r = 0; r < 64; ++r) { cur[r] = s; s += hist[r]; }
    }
    __syncthreads();
    if (t < 64) {
        int n = b * 64 + t;
        if (n < NN) {
            row_ptr[n] = cur[t];
            row_deg[n] = hist[t];
            dinv[n] = rsqrtf(wsum[t] + 1.0f);
        }
    }
    __syncthreads();
    for (int j = g0 + t; j < g1; j += 256) {
        int2 pk = stage[j];
        int r = (pk.x >> 16) & 63;
        int pos = atomicAdd(&cur[r], 1);
        csr[pos] = make_int2(pk.x & 0xFFFF, pk.y);
    }
}

// hp[N,64] = bf16( dinv[r] * (x[N,64] @ W[64,64]) ); 16 rows/block
__global__ __launch_bounds__(256) void gemm_pre_kernel(const float* __restrict__ x,
        const float* __restrict__ W, const float* __restrict__ dinv,
        unsigned short* __restrict__ hp) {
    __shared__ float xs[16][64];
    int t = threadIdx.x;
    int base = blockIdx.x * 16;
    for (int idx = t; idx < 16 * 64; idx += 256)
        xs[idx >> 6][idx & 63] = x[(size_t)(base + (idx >> 6)) * 64 + (idx & 63)];
    __syncthreads();
    int col = t & 63, rq = t >> 6;
    float wc[64];
#pragma unroll
    for (int k = 0; k < 64; ++k) wc[k] = W[k * 64 + col];
    float acc0 = 0.f, acc1 = 0.f, acc2 = 0.f, acc3 = 0.f;
#pragma unroll
    for (int k = 0; k < 64; ++k) {
        float wk = wc[k];
        acc0 += xs[rq     ][k] * wk;
        acc1 += xs[rq +  4][k] * wk;
        acc2 += xs[rq +  8][k] * wk;
        acc3 += xs[rq + 12][k] * wk;
    }
    int r = base + rq;
    hp[(size_t)(r     ) * 64 + col] = f2b(dinv[r     ] * acc0);
    hp[(size_t)(r +  4) * 64 + col] = f2b(dinv[r +  4] * acc1);
    hp[(size_t)(r +  8) * 64 + col] = f2b(dinv[r +  8] * acc2);
    hp[(size_t)(r + 12) * 64 + col] = f2b(dinv[r + 12] * acc3);
}

// gather body (quarter-wave per node): returns float4 aggregate incl. self term
__device__ __forceinline__ float4 gather_row(int n, int fq, int qbase,
        const int* __restrict__ row_ptr, const int* __restrict__ row_deg,
        const int2* __restrict__ csr, const uint2* __restrict__ hp64) {
    int s0 = row_ptr[n], s1 = s0 + row_deg[n];
    uint2 self = hp64[(size_t)n * 16 + fq];
    float ax = blo(self.x), ay = bhi(self.x), az = blo(self.y), aw = bhi(self.y);
    float bx = 0.f, by = 0.f, bz = 0.f, bw = 0.f;
    for (int base = s0; base < s1; base += 16) {
        int j = base + fq;
        int si = 0; float wl = 0.f;
        if (j < s1) {
            int2 pk = csr[j];
            si = pk.x;
            wl = __int_as_float(pk.y);
        }
        int m = s1 - base; if (m > 16) m = 16;
        int jj = 0;
        for (; jj + 4 <= m; jj += 4) {
            int a0 = __shfl(si, qbase + jj + 0); float w0 = __shfl(wl, qbase + jj + 0);
            int a1 = __shfl(si, qbase + jj + 1); float w1 = __shfl(wl, qbase + jj + 1);
            int a2 = __shfl(si, qbase + jj + 2); float w2 = __shfl(wl, qbase + jj + 2);
            int a3 = __shfl(si, qbase + jj + 3); float w3 = __shfl(wl, qbase + jj + 3);
            uint2 u0 = hp64[(size_t)a0 * 16 + fq];
            uint2 u1 = hp64[(size_t)a1 * 16 + fq];
            uint2 u2 = hp64[(size_t)a2 * 16 + fq];
            uint2 u3 = hp64[(size_t)a3 * 16 + fq];
            ax += w0 * blo(u0.x); ay += w0 * bhi(u0.x); az += w0 * blo(u0.y); aw += w0 * bhi(u0.y);
            bx += w1 * blo(u1.x); by += w1 * bhi(u1.x); bz += w1 * blo(u1.y); bw += w1 * bhi(u1.y);
            ax += w2 * blo(u2.x); ay += w2 * bhi(u2.x); az += w2 * blo(u2.y); aw += w2 * bhi(u2.y);
            bx += w3 * blo(u3.x); by += w3 * bhi(u3.x); bz += w3 * blo(u3.y); bw += w3 * bhi(u3.y);
        }
        for (; jj < m; ++jj) {
            int a0 = __shfl(si, qbase + jj); float w0 = __shfl(wl, qbase + jj);
            uint2 u0 = hp64[(size_t)a0 * 16 + fq];
            ax += w0 * blo(u0.x); ay += w0 * bhi(u0.x); az += w0 * blo(u0.y); aw += w0 * bhi(u0.y);
        }
    }
    return make_float4(ax + bx, ay + by, az + bz, aw + bw);
}

// fused: gather(hp_cur, bias_l) -> y = relu(...) -> hp_next = bf16(dinv * (y @ Wn))
__global__ __launch_bounds__(256) void fused_kernel(const int* __restrict__ row_ptr,
        const int* __restrict__ row_deg, const int2* __restrict__ csr,
        const float* __restrict__ dinv, const uint2* __restrict__ hp_cur,
        const float* __restrict__ bias, const float* __restrict__ Wn,
        unsigned short* __restrict__ hp_next) {
    __shared__ float ys[16][64];
    int t = threadIdx.x;
    int lane = t & 63, q = lane >> 4, fq = lane & 15;
    int ni = ((t >> 6) << 2) + q;
    int n = blockIdx.x * 16 + ni;
    float4 g = gather_row(n, fq, q << 4, row_ptr, row_deg, csr, hp_cur);
    float dv = dinv[n];
    float4 bb = ((const float4*)bias)[fq];
    float4 y;
    y.x = fmaxf(dv * g.x + bb.x, 0.f);
    y.y = fmaxf(dv * g.y + bb.y, 0.f);
    y.z = fmaxf(dv * g.z + bb.z, 0.f);
    y.w = fmaxf(dv * g.w + bb.w, 0.f);
    ((float4*)ys[ni])[fq] = y;
    __syncthreads();
    // gemm: 16x64 y-tile @ W -> hp_next rows of this block
    int col = lane, rq = t >> 6;
    float wc[64];
#pragma unroll
    for (int k = 0; k < 64; ++k) wc[k] = Wn[k * 64 + col];
    float a0 = 0.f, a1 = 0.f, a2 = 0.f, a3 = 0.f;
#pragma unroll
    for (int k = 0; k < 64; ++k) {
        float wk = wc[k];
        a0 += ys[rq     ][k] * wk;
        a1 += ys[rq +  4][k] * wk;
        a2 += ys[rq +  8][k] * wk;
        a3 += ys[rq + 12][k] * wk;
    }
    int r = blockIdx.x * 16 + rq;
    hp_next[(size_t)(r     ) * 64 + col] = f2b(dinv[r     ] * a0);
    hp_next[(size_t)(r +  4) * 64 + col] = f2b(dinv[r +  4] * a1);
    hp_next[(size_t)(r +  8) * 64 + col] = f2b(dinv[r +  8] * a2);
    hp_next[(size_t)(r + 12) * 64 + col] = f2b(dinv[r + 12] * a3);
}

// final layer: gather + bias + relu -> fp32 out
__global__ __launch_bounds__(256) void final_kernel(const int* __restrict__ row_ptr,
        const int* __restrict__ row_deg, const int2* __restrict__ csr,
        const float* __restrict__ dinv, const uint2* __restrict__ hp_cur,
        const float* __restrict__ bias, float* __restrict__ out) {
    int t = threadIdx.x;
    int lane = t & 63, q = lane >> 4, fq = lane & 15;
    int n = blockIdx.x * 16 + ((t >> 6) << 2) + q;
    float4 g = gather_row(n, fq, q << 4, row_ptr, row_deg, csr, hp_cur);
    float dv = dinv[n];
    float4 bb = ((const float4*)bias)[fq];
    float4 r;
    r.x = fmaxf(dv * g.x + bb.x, 0.f);
    r.y = fmaxf(dv * g.y + bb.y, 0.f);
    r.z = fmaxf(dv * g.z + bb.z, 0.f);
    r.w = fmaxf(dv * g.w + bb.w, 0.f);
    ((float4*)out)[(size_t)n * 16 + fq] = r;
}

extern "C" void kernel_launch(void* const* d_in, const int* in_sizes, int n_in,
                              void* d_out, int out_size, void* d_ws, size_t ws_size,
                              hipStream_t stream) {
    const float* x  = (const float*)d_in[0];
    const int*   ei = (const int*)d_in[1];    // int32 [2, NE] flat
    const float* ew = (const float*)d_in[2];
    const float* W0 = (const float*)d_in[3];
    const float* b0 = (const float*)d_in[4];
    const float* W1 = (const float*)d_in[5];
    const float* b1 = (const float*)d_in[6];
    const float* W2 = (const float*)d_in[7];
    const float* b2 = (const float*)d_in[8];
    float*       out = (float*)d_out;

    const int* src = ei;
    const int* dst = ei + NE;

    // workspace layout (int2 arrays first for 8B alignment), ~33 MB total
    int2*  stage   = (int2*)d_ws;                    // CAPTOT
    int2*  csr     = stage + CAPTOT;                 // CAPTOT
    int*   cursor  = (int*)(csr + CAPTOT);           // NB
    int*   row_ptr = cursor + NB;                    // NN
    int*   row_deg = row_ptr + NN;                   // NN
    float* dinv    = (float*)(row_deg + NN);         // NN
    unsigned short* hpA = (unsigned short*)(dinv + NN);  // NN*64 bf16 (6.4 MB)
    unsigned short* hpB = hpA + (size_t)NN * 64;         // NN*64 bf16 (6.4 MB)

    // ---- CSR build (once, shared by all 3 layers) ----
    k_init<<<1, 1024, 0, stream>>>(cursor);
    p12<<<NBLK, 256, 0, stream>>>(src, dst, ew, cursor, stage);
    p3_sort<<<NB, 256, 0, stream>>>(stage, cursor, csr, row_ptr, row_deg, dinv);

    // ---- layer pipeline: gemm0 -> fused(l0->l1) -> fused(l1->l2) -> final ----
    gemm_pre_kernel<<<NN / 16, 256, 0, stream>>>(x, W0, dinv, hpA);
    fused_kernel<<<NN / 16, 256, 0, stream>>>(row_ptr, row_deg, csr, dinv,
            (const uint2*)hpA, b0, W1, hpB);
    fused_kernel<<<NN / 16, 256, 0, stream>>>(row_ptr, row_deg, csr, dinv,
            (const uint2*)hpB, b1, W2, hpA);
    final_kernel<<<NN / 16, 256, 0, stream>>>(row_ptr, row_deg, csr, dinv,
            (const uint2*)hpA, b2, out);
}